// Round 15
// baseline (56.997 us; speedup 1.0000x reference)
//
#include <hip/hip_runtime.h>

#define BB 2
#define NN 4096
#define HH 8
#define DD 16
#define EE 128
#define LBLK 128
#define NSPL 8                   // L-split factor
#define NIV 2                    // barrier intervals per block (2 tiles each)

typedef _Float16 f16;
typedef _Float16 f16x4 __attribute__((ext_vector_type(4)));
typedef _Float16 f16x2 __attribute__((ext_vector_type(2)));
typedef _Float16 f16x8 __attribute__((ext_vector_type(8)));
typedef __fp16 h16x2 __attribute__((ext_vector_type(2)));
typedef float f32x4 __attribute__((ext_vector_type(4)));

// QSCALE = log2(e) / sqrt(128): folded into Qp so scores are exp2-ready
#define QSCALE 0.12751741f

// ---------------------------------------------------------------------------
// Kernel 1: project q/k/v (per-head 16x16 linear, x @ W^T), write f16.
//   Qp[b,h,n,d] (scaled), Kp[b,h,n,d], Vt[b,h,d,n]. Blocks 768+: Wo->f16.
// ---------------------------------------------------------------------------
__global__ __launch_bounds__(256) void proj_kernel(
    const float* __restrict__ vals, const float* __restrict__ keys,
    const float* __restrict__ query,
    const float* __restrict__ Wv, const float* __restrict__ Wk,
    const float* __restrict__ Wq, const float* __restrict__ Wo,
    f16* __restrict__ Qp, f16* __restrict__ Kp, f16* __restrict__ Vt,
    f16* __restrict__ Wo16)
{
    if (blockIdx.x >= 768) {
        const int i = (blockIdx.x - 768) * 256 + threadIdx.x;
        Wo16[i] = (f16)Wo[i];
        return;
    }
    __shared__ float W[256];
    const int p = blockIdx.x >> 8;   // 0=values,1=keys,2=query
    const float* Wsrc = (p == 0) ? Wv : ((p == 1) ? Wk : Wq);
    W[threadIdx.x] = Wsrc[threadIdx.x];
    __syncthreads();

    const int idx = ((blockIdx.x & 255) << 8) | threadIdx.x;  // 0..65535
    const int n = idx & 4095;
    const int h = (idx >> 12) & 7;
    const int b = idx >> 15;

    const float* xsrc = (p == 0) ? vals : ((p == 1) ? keys : query);
    const float4* xp = (const float4*)(xsrc + (size_t)(b * NN + n) * EE + h * DD);
    const float4 x0 = xp[0], x1 = xp[1], x2 = xp[2], x3 = xp[3];
    const float scale = (p == 2) ? QSCALE : 1.0f;

    alignas(16) f16 out[16];
    #pragma unroll
    for (int e = 0; e < 16; e++) {
        const float4* wr = (const float4*)(W + e * 16);
        const float4 w0 = wr[0], w1 = wr[1], w2 = wr[2], w3 = wr[3];
        float acc = x0.x * w0.x + x0.y * w0.y + x0.z * w0.z + x0.w * w0.w
                  + x1.x * w1.x + x1.y * w1.y + x1.z * w1.z + x1.w * w1.w
                  + x2.x * w2.x + x2.y * w2.y + x2.z * w2.z + x2.w * w2.w
                  + x3.x * w3.x + x3.y * w3.y + x3.z * w3.z + x3.w * w3.w;
        out[e] = (f16)(acc * scale);
    }

    if (p == 0) {
        f16* dst = Vt + (size_t)(b * HH + h) * DD * NN + n;
        #pragma unroll
        for (int e = 0; e < 16; e++) dst[(size_t)e * NN] = out[e];
    } else {
        f16* dst = ((p == 1) ? Kp : Qp) + (size_t)((b * HH + h) * NN + n) * DD;
        ((uint4*)dst)[0] = ((const uint4*)out)[0];
        ((uint4*)dst)[1] = ((const uint4*)out)[1];
    }
}

// ---------------------------------------------------------------------------
// Kernel 2: attention (r12-exact inner loop). 8-wave (512-thr) blocks,
// 32 q-rows/wave, split-L 8-WAY for scheduler backfill slack:
// grid 2048: bid = qt(4b) | bh(4b) | oct(3b) -- 8 blocks/CU of work.
// XCD pin: bid%8 = oct; per-XCD L2 holds all 16 bh slices of one oct
// (16 x 32 KB = 512 KB, L2-resident).
// LDS 32 KB ring, one barrier per 2 tiles; stage-loads before compute (T14);
// setprio around compute (T5); fragment-linear LDS (0 conflicts);
// ones-MFMA denominator; max-free softmax; f16 partials + f32 denom to ws.
// ---------------------------------------------------------------------------
__global__ __launch_bounds__(512, 8) void attn_kernel(
    const f16* __restrict__ Qp, const f16* __restrict__ Kp,
    const f16* __restrict__ Vt, f16* __restrict__ Oacc,
    float* __restrict__ den)
{
    __shared__ alignas(16) f16 Kl[2][2][2048];
    __shared__ alignas(16) f16 Vl[2][2][2048];

    const int tid = threadIdx.x;
    const int lane = tid & 63;
    const int wave = tid >> 6;
    const int r = lane & 15;
    const int g = lane >> 4;

    const int bid = blockIdx.x;
    const int oct = bid & 7;
    const int bh = (bid >> 3) & 15;
    const int qt = bid >> 7;
    const int q0 = qt * 256 + wave * 32;
    const int L0 = oct * (NN / NSPL);

    const int ti = tid >> 8;             // 0,1
    const int u = tid & 255;
    const bool isK = u < 128;
    const f16* gbase;
    int w0, w1;
    if (isK) {
        const int spair = u >> 6;
        const int lp = u & 63;
        const int rr = lp & 15, gg = lp >> 4;
        const int lam = 8 * (rr >> 2) + (rr & 3);
        gbase = Kp + ((size_t)bh * NN + L0 + ti * LBLK + 64 * spair + lam) * DD + 4 * gg;
        w0 = (2 * spair) * 512 + lp * 8;
        w1 = (2 * spair + 1) * 512 + lp * 8;
    } else {
        const int v = u - 128;
        gbase = Vt + ((size_t)bh * DD + (v & 15)) * NN + L0 + ti * LBLK
                   + 32 * (v >> 6) + 8 * ((v >> 4) & 3);
        w0 = v * 8;
        w1 = 1024 + v * 8;
    }
    const size_t gstep = isK ? (size_t)(2 * LBLK) * DD : (size_t)(2 * LBLK);

    const f16x4 qf0 = *(const f16x4*)(Qp + ((size_t)bh * NN + q0 + r) * DD + 4 * g);
    const f16x4 qf1 = *(const f16x4*)(Qp + ((size_t)bh * NN + q0 + 16 + r) * DD + 4 * g);

    f16x8 sA, sB;
#define STAGE_LOAD() { \
    if (isK) { \
        const f16x4 a0 = *(const f16x4*)(gbase + 0); \
        const f16x4 a1 = *(const f16x4*)(gbase + 64); \
        const f16x4 a2 = *(const f16x4*)(gbase + 512); \
        const f16x4 a3 = *(const f16x4*)(gbase + 576); \
        sA = __builtin_shufflevector(a0, a1, 0,1,2,3,4,5,6,7); \
        sB = __builtin_shufflevector(a2, a3, 0,1,2,3,4,5,6,7); \
    } else { \
        sA = *(const f16x8*)(gbase + 0); \
        sB = *(const f16x8*)(gbase + 64); \
    } \
    gbase += gstep; }

#define STAGE_WRITE(HALF) { \
    f16* wp = isK ? &Kl[HALF][ti][0] : &Vl[HALF][ti][0]; \
    *(f16x8*)(wp + w0) = sA; \
    *(f16x8*)(wp + w1) = sB; }

    STAGE_LOAD();
    STAGE_WRITE(0);
    __syncthreads();

    f32x4 acc0 = {0.f,0.f,0.f,0.f}, acc1 = {0.f,0.f,0.f,0.f};
    f32x4 dacc0 = {0.f,0.f,0.f,0.f}, dacc1 = {0.f,0.f,0.f,0.f};
    const f32x4 zz = {0.f,0.f,0.f,0.f};
    const f16x8 ones8 = {(f16)1.f,(f16)1.f,(f16)1.f,(f16)1.f,
                         (f16)1.f,(f16)1.f,(f16)1.f,(f16)1.f};

#define QKPV(QF, ACC, DACC) { \
    const f32x4 st0 = __builtin_amdgcn_mfma_f32_16x16x16f16(kfA, (QF), zz, 0, 0, 0); \
    const f32x4 st1 = __builtin_amdgcn_mfma_f32_16x16x16f16(kfB, (QF), zz, 0, 0, 0); \
    const float e0 = __builtin_amdgcn_exp2f(st0[0]); \
    const float e1 = __builtin_amdgcn_exp2f(st0[1]); \
    const float e2 = __builtin_amdgcn_exp2f(st0[2]); \
    const float e3 = __builtin_amdgcn_exp2f(st0[3]); \
    const float f0 = __builtin_amdgcn_exp2f(st1[0]); \
    const float f1 = __builtin_amdgcn_exp2f(st1[1]); \
    const float f2 = __builtin_amdgcn_exp2f(st1[2]); \
    const float f3 = __builtin_amdgcn_exp2f(st1[3]); \
    const h16x2 h0 = __builtin_amdgcn_cvt_pkrtz(e0, e1); \
    const h16x2 h1 = __builtin_amdgcn_cvt_pkrtz(e2, e3); \
    const h16x2 h2 = __builtin_amdgcn_cvt_pkrtz(f0, f1); \
    const h16x2 h3 = __builtin_amdgcn_cvt_pkrtz(f2, f3); \
    const f16x4 pA = __builtin_shufflevector( \
        __builtin_bit_cast(f16x2, h0), __builtin_bit_cast(f16x2, h1), 0, 1, 2, 3); \
    const f16x4 pB = __builtin_shufflevector( \
        __builtin_bit_cast(f16x2, h2), __builtin_bit_cast(f16x2, h3), 0, 1, 2, 3); \
    const f16x8 pf8 = __builtin_shufflevector(pA, pB, 0, 1, 2, 3, 4, 5, 6, 7); \
    ACC  = __builtin_amdgcn_mfma_f32_16x16x32_f16(vf8, pf8, ACC, 0, 0, 0); \
    DACC = __builtin_amdgcn_mfma_f32_16x16x32_f16(ones8, pf8, DACC, 0, 0, 0); }

    int half = 0;
    for (int iv = 0; iv < NIV; ++iv) {
        if (iv < NIV - 1) STAGE_LOAD();

        __builtin_amdgcn_s_setprio(1);
        #pragma unroll
        for (int t2 = 0; t2 < 2; ++t2) {
            const f16* Kb = &Kl[half][t2][0];
            const f16* Vb = &Vl[half][t2][0];
            #pragma unroll
            for (int s = 0; s < 4; ++s) {
                const f16x8 kf8 = *(const f16x8*)(Kb + s * 512 + lane * 8);
                const f16x8 vf8 = *(const f16x8*)(Vb + s * 512 + lane * 8);
                const f16x4 kfA = __builtin_shufflevector(kf8, kf8, 0, 1, 2, 3);
                const f16x4 kfB = __builtin_shufflevector(kf8, kf8, 4, 5, 6, 7);
                QKPV(qf0, acc0, dacc0)
                QKPV(qf1, acc1, dacc1)
            }
        }
        __builtin_amdgcn_s_setprio(0);

        if (iv < NIV - 1) STAGE_WRITE(half ^ 1);
        __syncthreads();
        half ^= 1;
    }
#undef QKPV
#undef STAGE_WRITE
#undef STAGE_LOAD

    const int b = bh >> 3, h = bh & 7;
    f16* OaccQ = Oacc + (size_t)oct * (BB * NN * EE);
    const f16x4 o0 = __builtin_shufflevector(
        __builtin_bit_cast(f16x2, __builtin_amdgcn_cvt_pkrtz(acc0[0], acc0[1])),
        __builtin_bit_cast(f16x2, __builtin_amdgcn_cvt_pkrtz(acc0[2], acc0[3])), 0, 1, 2, 3);
    const f16x4 o1 = __builtin_shufflevector(
        __builtin_bit_cast(f16x2, __builtin_amdgcn_cvt_pkrtz(acc1[0], acc1[1])),
        __builtin_bit_cast(f16x2, __builtin_amdgcn_cvt_pkrtz(acc1[2], acc1[3])), 0, 1, 2, 3);
    *(f16x4*)(OaccQ + ((size_t)(b * NN + q0 + r)) * EE + h * DD + 4 * g) = o0;
    *(f16x4*)(OaccQ + ((size_t)(b * NN + q0 + 16 + r)) * EE + h * DD + 4 * g) = o1;
    if (lane < 16) {
        den[(size_t)(oct * 16 + bh) * NN + q0 + lane] = dacc0[0];
        den[(size_t)(oct * 16 + bh) * NN + q0 + 16 + lane] = dacc1[0];
    }
}

// ---------------------------------------------------------------------------
// Kernel 3: combine 8 f16 partials + out[n,e] = (O/den) @ Wo^T + bo.
// r12 shape: grid 256 x 256, 2 n-tiles/block, e-split across wave pairs.
// ---------------------------------------------------------------------------
static __device__ __forceinline__ f32x4 cvt4(f16x4 x) {
    return (f32x4){(float)x[0], (float)x[1], (float)x[2], (float)x[3]};
}

__global__ __launch_bounds__(256) void outproj_kernel(
    const f16* __restrict__ Oacc, const float* __restrict__ den,
    const f16* __restrict__ Wo16, const float* __restrict__ bo,
    float* __restrict__ out)
{
    const int lane = threadIdx.x & 63;
    const int wave = threadIdx.x >> 6;
    const int r = lane & 15;
    const int g = lane >> 4;
    const int n0 = (blockIdx.x * 2 + (wave >> 1)) * 16;
    const int eh = (wave & 1) * 4;   // e-tile base (4 tiles of 16)

    const int n = n0 + r;            // 0..8191
    const int b = n >> 12;
    const int nn = n & 4095;
    const f16* Oa = Oacc + (size_t)n * EE;
    const size_t PSTRIDE = (size_t)BB * NN * EE;

    f32x4 acc[4];
    #pragma unroll
    for (int e = 0; e < 4; e++) acc[e] = (f32x4){0.f, 0.f, 0.f, 0.f};

    #pragma unroll
    for (int k0 = 0; k0 < 8; k0++) {
        // per-(row, head) inverse denominator; head == k0
        const size_t didx = (size_t)(b * 8 + k0) * NN + nn;
        float dsum = 0.f;
        #pragma unroll
        for (int p = 0; p < NSPL; p++) dsum += den[(size_t)p * 16 * NN + didx];
        const float inv = 1.0f / dsum;
        f32x4 xa = (f32x4){0.f, 0.f, 0.f, 0.f};
        #pragma unroll
        for (int p = 0; p < NSPL; p++)
            xa = xa + cvt4(*(const f16x4*)(Oa + (size_t)p * PSTRIDE + k0 * 16 + 4 * g));
        const float s0 = xa[0] * inv;
        const float s1 = xa[1] * inv;
        const float s2 = xa[2] * inv;
        const float s3 = xa[3] * inv;
        const f16x4 a = __builtin_shufflevector(
            __builtin_bit_cast(f16x2, __builtin_amdgcn_cvt_pkrtz(s0, s1)),
            __builtin_bit_cast(f16x2, __builtin_amdgcn_cvt_pkrtz(s2, s3)), 0, 1, 2, 3);
        #pragma unroll
        for (int e = 0; e < 4; e++) {
            const f16x4 bf = *(const f16x4*)(Wo16 + (size_t)((eh + e) * 16 + r) * EE + k0 * 16 + 4 * g);
            acc[e] = __builtin_amdgcn_mfma_f32_16x16x16f16(a, bf, acc[e], 0, 0, 0);
        }
    }

    #pragma unroll
    for (int e = 0; e < 4; e++) {
        const float bias = bo[(eh + e) * 16 + r];
        #pragma unroll
        for (int i = 0; i < 4; i++) {
            out[(size_t)(n0 + 4 * g + i) * EE + (eh + e) * 16 + r] = acc[e][i] + bias;
        }
    }
}

// ---------------------------------------------------------------------------
extern "C" void kernel_launch(void* const* d_in, const int* in_sizes, int n_in,
                              void* d_out, int out_size, void* d_ws, size_t ws_size,
                              hipStream_t stream)
{
    const float* vals  = (const float*)d_in[0];
    const float* keys  = (const float*)d_in[1];
    const float* query = (const float*)d_in[2];
    const float* Wv    = (const float*)d_in[3];
    const float* Wk    = (const float*)d_in[4];
    const float* Wq    = (const float*)d_in[5];
    const float* Wo    = (const float*)d_in[6];
    const float* bo    = (const float*)d_in[7];
    float* out = (float*)d_out;

    char* w = (char*)d_ws;
    f16*   Qp   = (f16*)(w);                        // 2 MB   [16][4096][16]
    f16*   Kp   = (f16*)(w + (2u << 20));           // 2 MB
    f16*   Vt   = (f16*)(w + (4u << 20));           // 2 MB   [16][16][4096]
    f16*   Wo16 = (f16*)(w + (6u << 20));           // 32 KB
    float* den  = (float*)(w + (6u << 20) + 65536); // 2 MB   [8][16][4096]
    f16*   Oacc = (f16*)(w + (9u << 20));           // 16 MB  [8][2][4096][128] f16

    hipLaunchKernelGGL(proj_kernel, dim3(832), dim3(256), 0, stream,
                       vals, keys, query, Wv, Wk, Wq, Wo, Qp, Kp, Vt, Wo16);
    hipLaunchKernelGGL(attn_kernel, dim3(2048), dim3(512), 0, stream,
                       Qp, Kp, Vt, Oacc, den);
    hipLaunchKernelGGL(outproj_kernel, dim3(256), dim3(256), 0, stream,
                       Oacc, den, Wo16, bo, out);
}

// Round 16
// 53.685 us; speedup vs baseline: 1.0617x; 1.0617x over previous
//
#include <hip/hip_runtime.h>

#define BB 2
#define NN 4096
#define HH 8
#define DD 16
#define EE 128
#define LBLK 128
#define NSPL 4                   // L-split factor
#define NIV 4                    // barrier intervals per block (2 tiles each)

typedef _Float16 f16;
typedef _Float16 f16x4 __attribute__((ext_vector_type(4)));
typedef _Float16 f16x2 __attribute__((ext_vector_type(2)));
typedef _Float16 f16x8 __attribute__((ext_vector_type(8)));
typedef __fp16 h16x2 __attribute__((ext_vector_type(2)));
typedef float f32x4 __attribute__((ext_vector_type(4)));

// QSCALE = log2(e) / sqrt(128): folded into Qp so scores are exp2-ready
#define QSCALE 0.12751741f

// ---------------------------------------------------------------------------
// Kernel 1: project q/k/v (per-head 16x16 linear, x @ W^T), write f16.
//   Qp[b,h,n,d] (scaled), Kp[b,h,n,d], Vt[b,h,d,n]. Blocks 768+: Wo->f16.
// ---------------------------------------------------------------------------
__global__ __launch_bounds__(256) void proj_kernel(
    const float* __restrict__ vals, const float* __restrict__ keys,
    const float* __restrict__ query,
    const float* __restrict__ Wv, const float* __restrict__ Wk,
    const float* __restrict__ Wq, const float* __restrict__ Wo,
    f16* __restrict__ Qp, f16* __restrict__ Kp, f16* __restrict__ Vt,
    f16* __restrict__ Wo16)
{
    if (blockIdx.x >= 768) {
        const int i = (blockIdx.x - 768) * 256 + threadIdx.x;
        Wo16[i] = (f16)Wo[i];
        return;
    }
    __shared__ float W[256];
    const int p = blockIdx.x >> 8;   // 0=values,1=keys,2=query
    const float* Wsrc = (p == 0) ? Wv : ((p == 1) ? Wk : Wq);
    W[threadIdx.x] = Wsrc[threadIdx.x];
    __syncthreads();

    const int idx = ((blockIdx.x & 255) << 8) | threadIdx.x;  // 0..65535
    const int n = idx & 4095;
    const int h = (idx >> 12) & 7;
    const int b = idx >> 15;

    const float* xsrc = (p == 0) ? vals : ((p == 1) ? keys : query);
    const float4* xp = (const float4*)(xsrc + (size_t)(b * NN + n) * EE + h * DD);
    const float4 x0 = xp[0], x1 = xp[1], x2 = xp[2], x3 = xp[3];
    const float scale = (p == 2) ? QSCALE : 1.0f;

    alignas(16) f16 out[16];
    #pragma unroll
    for (int e = 0; e < 16; e++) {
        const float4* wr = (const float4*)(W + e * 16);
        const float4 w0 = wr[0], w1 = wr[1], w2 = wr[2], w3 = wr[3];
        float acc = x0.x * w0.x + x0.y * w0.y + x0.z * w0.z + x0.w * w0.w
                  + x1.x * w1.x + x1.y * w1.y + x1.z * w1.z + x1.w * w1.w
                  + x2.x * w2.x + x2.y * w2.y + x2.z * w2.z + x2.w * w2.w
                  + x3.x * w3.x + x3.y * w3.y + x3.z * w3.z + x3.w * w3.w;
        out[e] = (f16)(acc * scale);
    }

    if (p == 0) {
        f16* dst = Vt + (size_t)(b * HH + h) * DD * NN + n;
        #pragma unroll
        for (int e = 0; e < 16; e++) dst[(size_t)e * NN] = out[e];
    } else {
        f16* dst = ((p == 1) ? Kp : Qp) + (size_t)((b * HH + h) * NN + n) * DD;
        ((uint4*)dst)[0] = ((const uint4*)out)[0];
        ((uint4*)dst)[1] = ((const uint4*)out)[1];
    }
}

// ---------------------------------------------------------------------------
// Kernel 2: attention (r12-exact, session best). 8-wave (512-thr) blocks,
// 32 q-rows/wave, split-L 4-way. grid 1024: bid = qt(4b) | bh(4b) | quarter(2b)
// (low bits pin one K/V slice's 16 qt-blocks to one XCD).
// LDS 32 KB ring, one barrier per 2 tiles; stage-loads before compute (T14);
// setprio around compute (T5); fragment-linear LDS (0 conflicts);
// ones-MFMA denominator; max-free softmax; f16 partials + f32 denom to ws.
// ---------------------------------------------------------------------------
__global__ __launch_bounds__(512, 8) void attn_kernel(
    const f16* __restrict__ Qp, const f16* __restrict__ Kp,
    const f16* __restrict__ Vt, f16* __restrict__ Oacc,
    float* __restrict__ den)
{
    __shared__ alignas(16) f16 Kl[2][2][2048];
    __shared__ alignas(16) f16 Vl[2][2][2048];

    const int tid = threadIdx.x;
    const int lane = tid & 63;
    const int wave = tid >> 6;
    const int r = lane & 15;
    const int g = lane >> 4;

    const int bid = blockIdx.x;
    const int quarter = bid & 3;
    const int bh = (bid >> 2) & 15;
    const int qt = bid >> 6;
    const int q0 = qt * 256 + wave * 32;
    const int L0 = quarter * (NN / NSPL);

    const int ti = tid >> 8;             // 0,1
    const int u = tid & 255;
    const bool isK = u < 128;
    const f16* gbase;
    int w0, w1;
    if (isK) {
        const int spair = u >> 6;
        const int lp = u & 63;
        const int rr = lp & 15, gg = lp >> 4;
        const int lam = 8 * (rr >> 2) + (rr & 3);
        gbase = Kp + ((size_t)bh * NN + L0 + ti * LBLK + 64 * spair + lam) * DD + 4 * gg;
        w0 = (2 * spair) * 512 + lp * 8;
        w1 = (2 * spair + 1) * 512 + lp * 8;
    } else {
        const int v = u - 128;
        gbase = Vt + ((size_t)bh * DD + (v & 15)) * NN + L0 + ti * LBLK
                   + 32 * (v >> 6) + 8 * ((v >> 4) & 3);
        w0 = v * 8;
        w1 = 1024 + v * 8;
    }
    const size_t gstep = isK ? (size_t)(2 * LBLK) * DD : (size_t)(2 * LBLK);

    const f16x4 qf0 = *(const f16x4*)(Qp + ((size_t)bh * NN + q0 + r) * DD + 4 * g);
    const f16x4 qf1 = *(const f16x4*)(Qp + ((size_t)bh * NN + q0 + 16 + r) * DD + 4 * g);

    f16x8 sA, sB;
#define STAGE_LOAD() { \
    if (isK) { \
        const f16x4 a0 = *(const f16x4*)(gbase + 0); \
        const f16x4 a1 = *(const f16x4*)(gbase + 64); \
        const f16x4 a2 = *(const f16x4*)(gbase + 512); \
        const f16x4 a3 = *(const f16x4*)(gbase + 576); \
        sA = __builtin_shufflevector(a0, a1, 0,1,2,3,4,5,6,7); \
        sB = __builtin_shufflevector(a2, a3, 0,1,2,3,4,5,6,7); \
    } else { \
        sA = *(const f16x8*)(gbase + 0); \
        sB = *(const f16x8*)(gbase + 64); \
    } \
    gbase += gstep; }

#define STAGE_WRITE(HALF) { \
    f16* wp = isK ? &Kl[HALF][ti][0] : &Vl[HALF][ti][0]; \
    *(f16x8*)(wp + w0) = sA; \
    *(f16x8*)(wp + w1) = sB; }

    STAGE_LOAD();
    STAGE_WRITE(0);
    __syncthreads();

    f32x4 acc0 = {0.f,0.f,0.f,0.f}, acc1 = {0.f,0.f,0.f,0.f};
    f32x4 dacc0 = {0.f,0.f,0.f,0.f}, dacc1 = {0.f,0.f,0.f,0.f};
    const f32x4 zz = {0.f,0.f,0.f,0.f};
    const f16x8 ones8 = {(f16)1.f,(f16)1.f,(f16)1.f,(f16)1.f,
                         (f16)1.f,(f16)1.f,(f16)1.f,(f16)1.f};

#define QKPV(QF, ACC, DACC) { \
    const f32x4 st0 = __builtin_amdgcn_mfma_f32_16x16x16f16(kfA, (QF), zz, 0, 0, 0); \
    const f32x4 st1 = __builtin_amdgcn_mfma_f32_16x16x16f16(kfB, (QF), zz, 0, 0, 0); \
    const float e0 = __builtin_amdgcn_exp2f(st0[0]); \
    const float e1 = __builtin_amdgcn_exp2f(st0[1]); \
    const float e2 = __builtin_amdgcn_exp2f(st0[2]); \
    const float e3 = __builtin_amdgcn_exp2f(st0[3]); \
    const float f0 = __builtin_amdgcn_exp2f(st1[0]); \
    const float f1 = __builtin_amdgcn_exp2f(st1[1]); \
    const float f2 = __builtin_amdgcn_exp2f(st1[2]); \
    const float f3 = __builtin_amdgcn_exp2f(st1[3]); \
    const h16x2 h0 = __builtin_amdgcn_cvt_pkrtz(e0, e1); \
    const h16x2 h1 = __builtin_amdgcn_cvt_pkrtz(e2, e3); \
    const h16x2 h2 = __builtin_amdgcn_cvt_pkrtz(f0, f1); \
    const h16x2 h3 = __builtin_amdgcn_cvt_pkrtz(f2, f3); \
    const f16x4 pA = __builtin_shufflevector( \
        __builtin_bit_cast(f16x2, h0), __builtin_bit_cast(f16x2, h1), 0, 1, 2, 3); \
    const f16x4 pB = __builtin_shufflevector( \
        __builtin_bit_cast(f16x2, h2), __builtin_bit_cast(f16x2, h3), 0, 1, 2, 3); \
    const f16x8 pf8 = __builtin_shufflevector(pA, pB, 0, 1, 2, 3, 4, 5, 6, 7); \
    ACC  = __builtin_amdgcn_mfma_f32_16x16x32_f16(vf8, pf8, ACC, 0, 0, 0); \
    DACC = __builtin_amdgcn_mfma_f32_16x16x32_f16(ones8, pf8, DACC, 0, 0, 0); }

    int half = 0;
    for (int iv = 0; iv < NIV; ++iv) {
        if (iv < NIV - 1) STAGE_LOAD();

        __builtin_amdgcn_s_setprio(1);
        #pragma unroll
        for (int t2 = 0; t2 < 2; ++t2) {
            const f16* Kb = &Kl[half][t2][0];
            const f16* Vb = &Vl[half][t2][0];
            #pragma unroll
            for (int s = 0; s < 4; ++s) {
                const f16x8 kf8 = *(const f16x8*)(Kb + s * 512 + lane * 8);
                const f16x8 vf8 = *(const f16x8*)(Vb + s * 512 + lane * 8);
                const f16x4 kfA = __builtin_shufflevector(kf8, kf8, 0, 1, 2, 3);
                const f16x4 kfB = __builtin_shufflevector(kf8, kf8, 4, 5, 6, 7);
                QKPV(qf0, acc0, dacc0)
                QKPV(qf1, acc1, dacc1)
            }
        }
        __builtin_amdgcn_s_setprio(0);

        if (iv < NIV - 1) STAGE_WRITE(half ^ 1);
        __syncthreads();
        half ^= 1;
    }
#undef QKPV
#undef STAGE_WRITE
#undef STAGE_LOAD

    const int b = bh >> 3, h = bh & 7;
    f16* OaccQ = Oacc + (size_t)quarter * (BB * NN * EE);
    const f16x4 o0 = __builtin_shufflevector(
        __builtin_bit_cast(f16x2, __builtin_amdgcn_cvt_pkrtz(acc0[0], acc0[1])),
        __builtin_bit_cast(f16x2, __builtin_amdgcn_cvt_pkrtz(acc0[2], acc0[3])), 0, 1, 2, 3);
    const f16x4 o1 = __builtin_shufflevector(
        __builtin_bit_cast(f16x2, __builtin_amdgcn_cvt_pkrtz(acc1[0], acc1[1])),
        __builtin_bit_cast(f16x2, __builtin_amdgcn_cvt_pkrtz(acc1[2], acc1[3])), 0, 1, 2, 3);
    *(f16x4*)(OaccQ + ((size_t)(b * NN + q0 + r)) * EE + h * DD + 4 * g) = o0;
    *(f16x4*)(OaccQ + ((size_t)(b * NN + q0 + 16 + r)) * EE + h * DD + 4 * g) = o1;
    if (lane < 16) {
        den[(size_t)(quarter * 16 + bh) * NN + q0 + lane] = dacc0[0];
        den[(size_t)(quarter * 16 + bh) * NN + q0 + 16 + lane] = dacc1[0];
    }
}

// ---------------------------------------------------------------------------
// Kernel 3: combine 4 f16 partials + out[n,e] = (O/den) @ Wo^T + bo.
// r12-exact: grid 256 x 256, 2 n-tiles/block, e-split across wave pairs.
// ---------------------------------------------------------------------------
static __device__ __forceinline__ f32x4 cvt4(f16x4 x) {
    return (f32x4){(float)x[0], (float)x[1], (float)x[2], (float)x[3]};
}

__global__ __launch_bounds__(256) void outproj_kernel(
    const f16* __restrict__ Oacc, const float* __restrict__ den,
    const f16* __restrict__ Wo16, const float* __restrict__ bo,
    float* __restrict__ out)
{
    const int lane = threadIdx.x & 63;
    const int wave = threadIdx.x >> 6;
    const int r = lane & 15;
    const int g = lane >> 4;
    const int n0 = (blockIdx.x * 2 + (wave >> 1)) * 16;
    const int eh = (wave & 1) * 4;   // e-tile base (4 tiles of 16)

    const int n = n0 + r;            // 0..8191
    const int b = n >> 12;
    const int nn = n & 4095;
    const f16* Oa0 = Oacc + (size_t)n * EE;
    const f16* Oa1 = Oa0 + (size_t)1 * (BB * NN * EE);
    const f16* Oa2 = Oa0 + (size_t)2 * (BB * NN * EE);
    const f16* Oa3 = Oa0 + (size_t)3 * (BB * NN * EE);

    f32x4 acc[4];
    #pragma unroll
    for (int e = 0; e < 4; e++) acc[e] = (f32x4){0.f, 0.f, 0.f, 0.f};

    #pragma unroll
    for (int k0 = 0; k0 < 8; k0++) {
        const size_t didx = (size_t)(b * 8 + k0) * NN + nn;
        const float inv = 1.0f / ((den[didx] + den[(size_t)16 * NN + didx])
                                + (den[(size_t)32 * NN + didx] + den[(size_t)48 * NN + didx]));
        const f32x4 xa = (cvt4(*(const f16x4*)(Oa0 + k0 * 16 + 4 * g))
                        + cvt4(*(const f16x4*)(Oa1 + k0 * 16 + 4 * g)))
                       + (cvt4(*(const f16x4*)(Oa2 + k0 * 16 + 4 * g))
                        + cvt4(*(const f16x4*)(Oa3 + k0 * 16 + 4 * g)));
        const float s0 = xa[0] * inv;
        const float s1 = xa[1] * inv;
        const float s2 = xa[2] * inv;
        const float s3 = xa[3] * inv;
        const f16x4 a = __builtin_shufflevector(
            __builtin_bit_cast(f16x2, __builtin_amdgcn_cvt_pkrtz(s0, s1)),
            __builtin_bit_cast(f16x2, __builtin_amdgcn_cvt_pkrtz(s2, s3)), 0, 1, 2, 3);
        #pragma unroll
        for (int e = 0; e < 4; e++) {
            const f16x4 bf = *(const f16x4*)(Wo16 + (size_t)((eh + e) * 16 + r) * EE + k0 * 16 + 4 * g);
            acc[e] = __builtin_amdgcn_mfma_f32_16x16x16f16(a, bf, acc[e], 0, 0, 0);
        }
    }

    #pragma unroll
    for (int e = 0; e < 4; e++) {
        const float bias = bo[(eh + e) * 16 + r];
        #pragma unroll
        for (int i = 0; i < 4; i++) {
            out[(size_t)(n0 + 4 * g + i) * EE + (eh + e) * 16 + r] = acc[e][i] + bias;
        }
    }
}

// ---------------------------------------------------------------------------
extern "C" void kernel_launch(void* const* d_in, const int* in_sizes, int n_in,
                              void* d_out, int out_size, void* d_ws, size_t ws_size,
                              hipStream_t stream)
{
    const float* vals  = (const float*)d_in[0];
    const float* keys  = (const float*)d_in[1];
    const float* query = (const float*)d_in[2];
    const float* Wv    = (const float*)d_in[3];
    const float* Wk    = (const float*)d_in[4];
    const float* Wq    = (const float*)d_in[5];
    const float* Wo    = (const float*)d_in[6];
    const float* bo    = (const float*)d_in[7];
    float* out = (float*)d_out;

    char* w = (char*)d_ws;
    f16*   Qp   = (f16*)(w);                        // 2 MB   [16][4096][16]
    f16*   Kp   = (f16*)(w + (2u << 20));           // 2 MB
    f16*   Vt   = (f16*)(w + (4u << 20));           // 2 MB   [16][16][4096]
    f16*   Wo16 = (f16*)(w + (6u << 20));           // 32 KB
    float* den  = (float*)(w + (6u << 20) + 65536); // 1 MB   [4][16][4096]
    f16*   Oacc = (f16*)(w + (8u << 20));           // 8 MB   [4][2][4096][128] f16

    hipLaunchKernelGGL(proj_kernel, dim3(832), dim3(256), 0, stream,
                       vals, keys, query, Wv, Wk, Wq, Wo, Qp, Kp, Vt, Wo16);
    hipLaunchKernelGGL(attn_kernel, dim3(1024), dim3(512), 0, stream,
                       Qp, Kp, Vt, Oacc, den);
    hipLaunchKernelGGL(outproj_kernel, dim3(256), dim3(256), 0, stream,
                       Oacc, den, Wo16, bo, out);
}